// Round 1
// baseline (302.178 us; speedup 1.0000x reference)
//
#include <hip/hip_runtime.h>
#include <stdint.h>

typedef __bf16 bf16x8 __attribute__((ext_vector_type(8)));
typedef float f32x4 __attribute__((ext_vector_type(4)));
typedef float float4v __attribute__((ext_vector_type(4)));
typedef unsigned short u16x4 __attribute__((ext_vector_type(4)));
typedef unsigned short u16x8 __attribute__((ext_vector_type(8)));

#define DEVI __device__ __forceinline__

static constexpr int Bv = 2, Sv = 4096, Ev = 512, Hv = 8, Dv = 64;
static constexpr int Mv = Bv * Sv;   // 8192
static constexpr int N3v = 3 * Ev;   // 1536

DEVI unsigned short f2bf(float f) {
    unsigned int u = __builtin_bit_cast(unsigned int, f);
    u += 0x7fffu + ((u >> 16) & 1u);
    return (unsigned short)(u >> 16);
}

DEVI void gload16(const void* src, void* lds) {
    __builtin_amdgcn_global_load_lds(
        (const __attribute__((address_space(1))) unsigned int*)src,
        (__attribute__((address_space(3))) unsigned int*)lds,
        16, 0, 0);
}

// ---------------- convert fp32 -> bf16 (flat) ----------------
__global__ __launch_bounds__(256) void k_convert(const float* __restrict__ in,
                                                 unsigned short* __restrict__ out, int n4) {
    int i = blockIdx.x * 256 + threadIdx.x;
    int stride = gridDim.x * 256;
    for (; i < n4; i += stride) {
        float4v v = ((const float4v*)in)[i];
        u16x4 o;
        o[0] = f2bf(v[0]); o[1] = f2bf(v[1]); o[2] = f2bf(v[2]); o[3] = f2bf(v[3]);
        ((u16x4*)out)[i] = o;
    }
}

// ---------------- transpose+convert: in fp32 [K][N] -> out bf16 [N][K] ----------------
__global__ __launch_bounds__(256) void k_tconv(const float* __restrict__ in,
                                               unsigned short* __restrict__ out, int K, int N) {
    __shared__ float lds[32][36];
    int tilesN = N >> 5;
    int tn = blockIdx.x % tilesN, tk = blockIdx.x / tilesN;
    int k0 = tk << 5, n0 = tn << 5;
    int t = threadIdx.x;
    int r = t >> 3, c4 = (t & 7) << 2;
    float4v v = *(const float4v*)(in + (size_t)(k0 + r) * N + n0 + c4);
    *(float4v*)&lds[r][c4] = v;
    __syncthreads();
    int nn = t >> 3, kc = (t & 7) << 2;
    u16x4 o;
#pragma unroll
    for (int j = 0; j < 4; ++j) o[j] = f2bf(lds[kc + j][nn]);
    *(u16x4*)(out + (size_t)(n0 + nn) * K + k0 + kc) = o;
}

// ---------------- GEMM 128x128 tile, BK=64, bf16 MFMA ----------------
// A [M][K] bf16, Bt [N][K] bf16.  EPI 0: QKV scatter. EPI 1: proj+residual (fp32 out)
template <int EPI>
__global__ __launch_bounds__(256) void k_gemm(
    const unsigned short* __restrict__ A, const unsigned short* __restrict__ Bt,
    int M, int N, int K, const float* __restrict__ bias,
    unsigned short* __restrict__ Qb, unsigned short* __restrict__ Kb,
    unsigned short* __restrict__ Vb,
    const float* __restrict__ xres, float* __restrict__ outf) {
    __shared__ char smem[32768];
    char* As = smem;
    char* Bs = smem + 16384;
    int nbt = N >> 7;
    int mb = blockIdx.x / nbt, nbi = blockIdx.x % nbt;
    int m0 = mb << 7, n0 = nbi << 7;
    int tid = threadIdx.x, lane = tid & 63, wave = tid >> 6;
    int wr = wave >> 1, wc = wave & 1;

    f32x4 acc[4][4];
    f32x4 zero = {0.f, 0.f, 0.f, 0.f};
#pragma unroll
    for (int a = 0; a < 4; ++a)
#pragma unroll
        for (int b = 0; b < 4; ++b) acc[a][b] = zero;

    for (int kt = 0; kt < K; kt += 64) {
        __syncthreads();
#pragma unroll
        for (int j = 0; j < 4; ++j) {
            int la = (((wave << 2) + j) << 10) + lane * 16;
            int r = la >> 7, cb = la & 127;
            int cbs = cb ^ ((r & 7) << 4);
            gload16((const char*)(A + (size_t)(m0 + r) * K + kt) + cbs,
                    As + (((wave << 2) + j) << 10));
            gload16((const char*)(Bt + (size_t)(n0 + r) * K + kt) + cbs,
                    Bs + (((wave << 2) + j) << 10));
        }
        asm volatile("s_waitcnt vmcnt(0)" ::: "memory");
        __syncthreads();

        bf16x8 af[4][2], bfr[4][2];
#pragma unroll
        for (int rf = 0; rf < 4; ++rf)
#pragma unroll
            for (int c = 0; c < 2; ++c) {
                int row = (wr << 6) + (rf << 4) + (lane & 15);
                int col = (c << 6) + ((lane >> 4) << 4);
                af[rf][c] = *(const bf16x8*)(As + row * 128 + (col ^ ((row & 7) << 4)));
                int rowb = (wc << 6) + (rf << 4) + (lane & 15);
                bfr[rf][c] = *(const bf16x8*)(Bs + rowb * 128 + (col ^ ((rowb & 7) << 4)));
            }
#pragma unroll
        for (int rf = 0; rf < 4; ++rf)
#pragma unroll
            for (int nf = 0; nf < 4; ++nf)
#pragma unroll
                for (int c = 0; c < 2; ++c)
                    acc[rf][nf] = __builtin_amdgcn_mfma_f32_16x16x32_bf16(
                        af[rf][c], bfr[nf][c], acc[rf][nf], 0, 0, 0);
    }

#pragma unroll
    for (int rf = 0; rf < 4; ++rf)
#pragma unroll
        for (int nf = 0; nf < 4; ++nf)
#pragma unroll
            for (int i = 0; i < 4; ++i) {
                int row = m0 + (wr << 6) + (rf << 4) + ((lane >> 4) << 2) + i;
                int col = n0 + (wc << 6) + (nf << 4) + (lane & 15);
                float v = acc[rf][nf][i] + bias[col];
                if (EPI == 0) {
                    int reg = col >> 9, hd = col & 511;
                    int h = hd >> 6, d = hd & 63;
                    int b = row >> 12, s = row & 4095;
                    size_t idx = ((size_t)((b << 3) + h) * Sv + s) * Dv + d;
                    if (reg == 0)      Qb[idx] = f2bf(v * 0.125f);
                    else if (reg == 1) Kb[idx] = f2bf(v);
                    else               Vb[idx] = f2bf(v);
                } else {
                    v += xres[(size_t)row * N + col];
                    outf[(size_t)row * N + col] = v;
                }
            }
}

// ---------------- V [bh][s][d] -> Vt [bh][d][s] ----------------
__global__ __launch_bounds__(256) void k_transpose_v(const unsigned short* __restrict__ V,
                                                     unsigned short* __restrict__ Vt) {
    __shared__ char lds[8192];
    int bh = blockIdx.x >> 6, st = blockIdx.x & 63;
    int s0 = st << 6;
    int t = threadIdx.x;
#pragma unroll
    for (int j = 0; j < 2; ++j) {
        int r = (t >> 3) + (j << 5);
        int cb = (t & 7) << 4;
        u16x8 v = *(const u16x8*)(V + ((size_t)bh * Sv + s0 + r) * Dv + (cb >> 1));
        *(u16x8*)(lds + r * 128 + (cb ^ ((r & 7) << 4))) = v;
    }
    __syncthreads();
#pragma unroll
    for (int j = 0; j < 2; ++j) {
        int d = (t >> 3) + (j << 5);
        int ss = (t & 7) << 3;
        u16x8 o;
#pragma unroll
        for (int k = 0; k < 8; ++k) {
            int s = ss + k;
            o[k] = *(const unsigned short*)(lds + s * 128 + ((d * 2) ^ ((s & 7) << 4)));
        }
        *(u16x8*)(Vt + ((size_t)bh * Dv + d) * Sv + s0 + ss) = o;
    }
}

// ---------------- flash attention ----------------
__global__ __launch_bounds__(256) void k_attn(const unsigned short* __restrict__ Qb,
                                              const unsigned short* __restrict__ Kb,
                                              const unsigned short* __restrict__ Vtb,
                                              unsigned short* __restrict__ ctx) {
    __shared__ char smem[24576];
    char* Ks = smem;          // 8KB [kv][128B]
    char* Vs = smem + 8192;   // 8KB [d][128B]
    int bh = blockIdx.x >> 6, qt = blockIdx.x & 63;
    int b = bh >> 3, h = bh & 7;
    int q0 = qt << 6;
    int tid = threadIdx.x, lane = tid & 63, wave = tid >> 6;
    char* Ps = smem + 16384 + wave * 2048;

    int qrow = q0 + (wave << 4) + (lane & 15);
    bf16x8 qf[2];
#pragma unroll
    for (int c = 0; c < 2; ++c)
        qf[c] = *(const bf16x8*)(Qb + ((size_t)bh * Sv + qrow) * Dv + (c << 5) + ((lane >> 4) << 3));

    float m[4], l[4];
    f32x4 o[4];
    f32x4 zero = {0.f, 0.f, 0.f, 0.f};
#pragma unroll
    for (int i = 0; i < 4; ++i) { m[i] = -1e30f; l[i] = 0.f; }
#pragma unroll
    for (int nf = 0; nf < 4; ++nf) o[nf] = zero;

    for (int kt = 0; kt < 64; ++kt) {
        int kv0 = kt << 6;
        __syncthreads();
#pragma unroll
        for (int j = 0; j < 4; ++j) {
            int off = ((wave << 2) + j) << 10;
            int loff = off + lane * 16;
            if (off < 8192) {
                int r = loff >> 7, cb = loff & 127;
                gload16((const char*)(Kb + ((size_t)bh * Sv + kv0 + r) * Dv) +
                            (cb ^ ((r & 7) << 4)),
                        smem + off);
            } else {
                int lo2 = loff - 8192;
                int r = lo2 >> 7, cb = lo2 & 127;
                gload16((const char*)(Vtb + ((size_t)bh * Dv + r) * Sv + kv0) +
                            (cb ^ ((r & 7) << 4)),
                        smem + off);
            }
        }
        asm volatile("s_waitcnt vmcnt(0)" ::: "memory");
        __syncthreads();

        // QK^T
        f32x4 sc[4];
#pragma unroll
        for (int nf = 0; nf < 4; ++nf) {
            sc[nf] = zero;
#pragma unroll
            for (int c = 0; c < 2; ++c) {
                int kr = (nf << 4) + (lane & 15);
                int col = (c << 6) + ((lane >> 4) << 4);
                bf16x8 kf = *(const bf16x8*)(Ks + kr * 128 + (col ^ ((kr & 7) << 4)));
                sc[nf] = __builtin_amdgcn_mfma_f32_16x16x32_bf16(qf[c], kf, sc[nf], 0, 0, 0);
            }
        }
        // online softmax (rows live in 16-lane groups)
        float pm[4];
#pragma unroll
        for (int i = 0; i < 4; ++i)
            pm[i] = fmaxf(fmaxf(sc[0][i], sc[1][i]), fmaxf(sc[2][i], sc[3][i]));
#pragma unroll
        for (int off = 1; off < 16; off <<= 1)
#pragma unroll
            for (int i = 0; i < 4; ++i) pm[i] = fmaxf(pm[i], __shfl_xor(pm[i], off, 64));
        float corr[4];
#pragma unroll
        for (int i = 0; i < 4; ++i) {
            float nm = fmaxf(m[i], pm[i]);
            corr[i] = __expf(m[i] - nm);
            m[i] = nm;
        }
        float ps[4] = {0.f, 0.f, 0.f, 0.f};
#pragma unroll
        for (int nf = 0; nf < 4; ++nf)
#pragma unroll
            for (int i = 0; i < 4; ++i) {
                float p = __expf(sc[nf][i] - m[i]);
                sc[nf][i] = p;
                ps[i] += p;
            }
#pragma unroll
        for (int off = 1; off < 16; off <<= 1)
#pragma unroll
            for (int i = 0; i < 4; ++i) ps[i] += __shfl_xor(ps[i], off, 64);
#pragma unroll
        for (int i = 0; i < 4; ++i) l[i] = l[i] * corr[i] + ps[i];
#pragma unroll
        for (int nf = 0; nf < 4; ++nf)
#pragma unroll
            for (int i = 0; i < 4; ++i) o[nf][i] *= corr[i];
        // P -> per-wave LDS (bf16, swizzled)
#pragma unroll
        for (int nf = 0; nf < 4; ++nf)
#pragma unroll
            for (int i = 0; i < 4; ++i) {
                int row = ((lane >> 4) << 2) + i;
                int colb = ((nf << 4) + (lane & 15)) << 1;
                *(unsigned short*)(Ps + row * 128 + (colb ^ ((row & 7) << 4))) = f2bf(sc[nf][i]);
            }
        // PV
#pragma unroll
        for (int c = 0; c < 2; ++c) {
            int prow = lane & 15;
            int colb = (c << 6) + ((lane >> 4) << 4);
            bf16x8 pf = *(const bf16x8*)(Ps + prow * 128 + (colb ^ ((prow & 7) << 4)));
#pragma unroll
            for (int nf = 0; nf < 4; ++nf) {
                int dr = (nf << 4) + (lane & 15);
                bf16x8 vf = *(const bf16x8*)(Vs + dr * 128 + (colb ^ ((dr & 7) << 4)));
                o[nf] = __builtin_amdgcn_mfma_f32_16x16x32_bf16(pf, vf, o[nf], 0, 0, 0);
            }
        }
    }

#pragma unroll
    for (int nf = 0; nf < 4; ++nf)
#pragma unroll
        for (int i = 0; i < 4; ++i) {
            int s = q0 + (wave << 4) + ((lane >> 4) << 2) + i;
            int col = (h << 6) + (nf << 4) + (lane & 15);
            ctx[((size_t)b * Sv + s) * Ev + col] = f2bf(o[nf][i] / l[i]);
        }
}

// ---------------- LayerNorm (1 wave / row of 512) ----------------
__global__ __launch_bounds__(256) void k_ln(const float* __restrict__ in,
                                            const float* __restrict__ g,
                                            const float* __restrict__ bta,
                                            float* __restrict__ out) {
    int wave = threadIdx.x >> 6, lane = threadIdx.x & 63;
    size_t row = (size_t)blockIdx.x * 4 + wave;
    const float* p = in + row * 512 + lane * 8;
    float4v v0 = *(const float4v*)p;
    float4v v1 = *(const float4v*)(p + 4);
    float s = 0.f, q = 0.f;
#pragma unroll
    for (int j = 0; j < 4; ++j) {
        s += v0[j] + v1[j];
        q += v0[j] * v0[j] + v1[j] * v1[j];
    }
#pragma unroll
    for (int off = 1; off < 64; off <<= 1) {
        s += __shfl_xor(s, off, 64);
        q += __shfl_xor(q, off, 64);
    }
    float mu = s * (1.f / 512.f);
    float var = q * (1.f / 512.f) - mu * mu;
    float rs = rsqrtf(var + 1e-5f);
    int c = lane * 8;
    float4v o0, o1;
#pragma unroll
    for (int j = 0; j < 4; ++j) {
        o0[j] = (v0[j] - mu) * rs * g[c + j] + bta[c + j];
        o1[j] = (v1[j] - mu) * rs * g[c + 4 + j] + bta[c + 4 + j];
    }
    *(float4v*)(out + row * 512 + c) = o0;
    *(float4v*)(out + row * 512 + c + 4) = o1;
}

extern "C" void kernel_launch(void* const* d_in, const int* in_sizes, int n_in,
                              void* d_out, int out_size, void* d_ws, size_t ws_size,
                              hipStream_t stream) {
    const float* x     = (const float*)d_in[0];
    const float* qkv_w = (const float*)d_in[1];
    const float* qkv_b = (const float*)d_in[2];
    const float* out_w = (const float*)d_in[3];
    const float* out_b = (const float*)d_in[4];
    const float* ln_g  = (const float*)d_in[5];
    const float* ln_b  = (const float*)d_in[6];
    float* out = (float*)d_out;
    char* ws = (char*)d_ws;

    unsigned short* xb    = (unsigned short*)(ws);              // 8 MB
    unsigned short* wqkvT = (unsigned short*)(ws + 8388608);    // 1.5 MB
    unsigned short* owT   = (unsigned short*)(ws + 9961472);    // 0.5 MB
    unsigned short* Qb    = (unsigned short*)(ws + 10485760);   // 8 MB
    unsigned short* Kb    = (unsigned short*)(ws + 18874368);   // 8 MB
    unsigned short* Vb    = (unsigned short*)(ws + 27262976);   // 8 MB
    unsigned short* Vtb   = (unsigned short*)(ws + 35651584);   // 8 MB
    unsigned short* ctxb  = (unsigned short*)(ws + 44040192);   // 8 MB
    float* tmp            = (float*)(ws + 52428800);            // 16 MB

    k_convert<<<2048, 256, 0, stream>>>(x, xb, Mv * Ev / 4);
    k_tconv<<<(512 / 32) * (1536 / 32), 256, 0, stream>>>(qkv_w, wqkvT, 512, 1536);
    k_tconv<<<(512 / 32) * (512 / 32), 256, 0, stream>>>(out_w, owT, 512, 512);
    k_gemm<0><<<(Mv / 128) * (N3v / 128), 256, 0, stream>>>(
        xb, wqkvT, Mv, N3v, Ev, qkv_b, Qb, Kb, Vb, nullptr, nullptr);
    k_transpose_v<<<16 * 64, 256, 0, stream>>>(Vb, Vtb);
    k_attn<<<16 * 64, 256, 0, stream>>>(Qb, Kb, Vtb, ctxb);
    k_gemm<1><<<(Mv / 128) * (Ev / 128), 256, 0, stream>>>(
        ctxb, owT, Mv, Ev, Ev, out_b, nullptr, nullptr, nullptr, x, tmp);
    k_ln<<<Mv / 4, 256, 0, stream>>>(tmp, ln_g, ln_b, out);
}

// Round 2
// 247.621 us; speedup vs baseline: 1.2203x; 1.2203x over previous
//
#include <hip/hip_runtime.h>
#include <stdint.h>

typedef __bf16 bf16x8 __attribute__((ext_vector_type(8)));
typedef float f32x4 __attribute__((ext_vector_type(4)));
typedef float float4v __attribute__((ext_vector_type(4)));
typedef unsigned short u16x4 __attribute__((ext_vector_type(4)));
typedef unsigned short u16x8 __attribute__((ext_vector_type(8)));
typedef unsigned int u32x4v __attribute__((ext_vector_type(4)));

#define DEVI __device__ __forceinline__

static constexpr int Bv = 2, Sv = 4096, Ev = 512, Hv = 8, Dv = 64;
static constexpr int Mv = Bv * Sv;   // 8192
static constexpr int N3v = 3 * Ev;   // 1536
// Q pre-scale: D^-0.5 * log2(e) so softmax runs in exp2 domain
static constexpr float QSCALE = 0.125f * 1.4426950408889634f;

DEVI unsigned short f2bf(float f) {
    unsigned int u = __builtin_bit_cast(unsigned int, f);
    u += 0x7fffu + ((u >> 16) & 1u);
    return (unsigned short)(u >> 16);
}

DEVI unsigned int cvtpk(float lo, float hi) {
    unsigned int r;
    asm("v_cvt_pk_bf16_f32 %0, %1, %2" : "=v"(r) : "v"(lo), "v"(hi));
    return r;
}

DEVI void gload16(const void* src, void* lds) {
    __builtin_amdgcn_global_load_lds(
        (const __attribute__((address_space(1))) unsigned int*)src,
        (__attribute__((address_space(3))) unsigned int*)lds,
        16, 0, 0);
}

// ---------------- convert fp32 -> bf16 (flat) ----------------
__global__ __launch_bounds__(256) void k_convert(const float* __restrict__ in,
                                                 unsigned short* __restrict__ out, int n4) {
    int i = blockIdx.x * 256 + threadIdx.x;
    int stride = gridDim.x * 256;
    for (; i < n4; i += stride) {
        float4v v = ((const float4v*)in)[i];
        u16x4 o;
        o[0] = f2bf(v[0]); o[1] = f2bf(v[1]); o[2] = f2bf(v[2]); o[3] = f2bf(v[3]);
        ((u16x4*)out)[i] = o;
    }
}

// ---------------- transpose+convert: in fp32 [K][N] -> out bf16 [N][K] ----------------
__global__ __launch_bounds__(256) void k_tconv(const float* __restrict__ in,
                                               unsigned short* __restrict__ out, int K, int N) {
    __shared__ float lds[32][36];
    int tilesN = N >> 5;
    int tn = blockIdx.x % tilesN, tk = blockIdx.x / tilesN;
    int k0 = tk << 5, n0 = tn << 5;
    int t = threadIdx.x;
    int r = t >> 3, c4 = (t & 7) << 2;
    float4v v = *(const float4v*)(in + (size_t)(k0 + r) * N + n0 + c4);
    *(float4v*)&lds[r][c4] = v;
    __syncthreads();
    int nn = t >> 3, kc = (t & 7) << 2;
    u16x4 o;
#pragma unroll
    for (int j = 0; j < 4; ++j) o[j] = f2bf(lds[kc + j][nn]);
    *(u16x4*)(out + (size_t)(n0 + nn) * K + k0 + kc) = o;
}

// ---------------- GEMM 128x128 tile, BK=64, bf16 MFMA ----------------
template <int EPI>
__global__ __launch_bounds__(256) void k_gemm(
    const unsigned short* __restrict__ A, const unsigned short* __restrict__ Bt,
    int M, int N, int K, const float* __restrict__ bias,
    unsigned short* __restrict__ Qb, unsigned short* __restrict__ Kb,
    unsigned short* __restrict__ Vb,
    const float* __restrict__ xres, float* __restrict__ outf) {
    __shared__ char smem[32768];
    char* As = smem;
    char* Bs = smem + 16384;
    int nbt = N >> 7;
    int mb = blockIdx.x / nbt, nbi = blockIdx.x % nbt;
    int m0 = mb << 7, n0 = nbi << 7;
    int tid = threadIdx.x, lane = tid & 63, wave = tid >> 6;
    int wr = wave >> 1, wc = wave & 1;

    f32x4 acc[4][4];
    f32x4 zero = {0.f, 0.f, 0.f, 0.f};
#pragma unroll
    for (int a = 0; a < 4; ++a)
#pragma unroll
        for (int b = 0; b < 4; ++b) acc[a][b] = zero;

    for (int kt = 0; kt < K; kt += 64) {
        __syncthreads();
#pragma unroll
        for (int j = 0; j < 4; ++j) {
            int la = (((wave << 2) + j) << 10) + lane * 16;
            int r = la >> 7, cb = la & 127;
            int cbs = cb ^ ((r & 7) << 4);
            gload16((const char*)(A + (size_t)(m0 + r) * K + kt) + cbs,
                    As + (((wave << 2) + j) << 10));
            gload16((const char*)(Bt + (size_t)(n0 + r) * K + kt) + cbs,
                    Bs + (((wave << 2) + j) << 10));
        }
        asm volatile("s_waitcnt vmcnt(0)" ::: "memory");
        __syncthreads();

        bf16x8 af[4][2], bfr[4][2];
#pragma unroll
        for (int rf = 0; rf < 4; ++rf)
#pragma unroll
            for (int c = 0; c < 2; ++c) {
                int row = (wr << 6) + (rf << 4) + (lane & 15);
                int col = (c << 6) + ((lane >> 4) << 4);
                af[rf][c] = *(const bf16x8*)(As + row * 128 + (col ^ ((row & 7) << 4)));
                int rowb = (wc << 6) + (rf << 4) + (lane & 15);
                bfr[rf][c] = *(const bf16x8*)(Bs + rowb * 128 + (col ^ ((rowb & 7) << 4)));
            }
#pragma unroll
        for (int rf = 0; rf < 4; ++rf)
#pragma unroll
            for (int nf = 0; nf < 4; ++nf)
#pragma unroll
                for (int c = 0; c < 2; ++c)
                    acc[rf][nf] = __builtin_amdgcn_mfma_f32_16x16x32_bf16(
                        af[rf][c], bfr[nf][c], acc[rf][nf], 0, 0, 0);
    }

#pragma unroll
    for (int rf = 0; rf < 4; ++rf)
#pragma unroll
        for (int nf = 0; nf < 4; ++nf)
#pragma unroll
            for (int i = 0; i < 4; ++i) {
                int row = m0 + (wr << 6) + (rf << 4) + ((lane >> 4) << 2) + i;
                int col = n0 + (wc << 6) + (nf << 4) + (lane & 15);
                float v = acc[rf][nf][i] + bias[col];
                if (EPI == 0) {
                    int reg = col >> 9, hd = col & 511;
                    int h = hd >> 6, d = hd & 63;
                    int b = row >> 12, s = row & 4095;
                    size_t idx = ((size_t)((b << 3) + h) * Sv + s) * Dv + d;
                    if (reg == 0)      Qb[idx] = f2bf(v * QSCALE);
                    else if (reg == 1) Kb[idx] = f2bf(v);
                    else               Vb[idx] = f2bf(v);
                } else {
                    v += xres[(size_t)row * N + col];
                    outf[(size_t)row * N + col] = v;
                }
            }
}

// ---------------- V [bh][s][d] -> Vt [bh][d][s] ----------------
__global__ __launch_bounds__(256) void k_transpose_v(const unsigned short* __restrict__ V,
                                                     unsigned short* __restrict__ Vt) {
    __shared__ char lds[8192];
    int bh = blockIdx.x >> 6, st = blockIdx.x & 63;
    int s0 = st << 6;
    int t = threadIdx.x;
#pragma unroll
    for (int j = 0; j < 2; ++j) {
        int r = (t >> 3) + (j << 5);
        int cb = (t & 7) << 4;
        u16x8 v = *(const u16x8*)(V + ((size_t)bh * Sv + s0 + r) * Dv + (cb >> 1));
        *(u16x8*)(lds + r * 128 + (cb ^ ((r & 7) << 4))) = v;
    }
    __syncthreads();
#pragma unroll
    for (int j = 0; j < 2; ++j) {
        int d = (t >> 3) + (j << 5);
        int ss = (t & 7) << 3;
        u16x8 o;
#pragma unroll
        for (int k = 0; k < 8; ++k) {
            int s = ss + k;
            o[k] = *(const unsigned short*)(lds + s * 128 + ((d * 2) ^ ((s & 7) << 4)));
        }
        *(u16x8*)(Vt + ((size_t)bh * Dv + d) * Sv + s0 + ss) = o;
    }
}

// ---------------- flash attention: swapped QK^T, in-register softmax ----------------
// P^T in registers: q = lane&15, kv(within 16-tile nf) = 4*(lane>>4)+i
__global__ __launch_bounds__(256) void k_attn(const unsigned short* __restrict__ Qb,
                                              const unsigned short* __restrict__ Kb,
                                              const unsigned short* __restrict__ Vtb,
                                              unsigned short* __restrict__ ctx) {
    __shared__ char smem[32768];  // 2 bufs x (K 8KB + Vt 8KB)
    int bh = blockIdx.x >> 6, qt = blockIdx.x & 63;
    int b = bh >> 3, h = bh & 7;
    int q0 = qt << 6;
    int tid = threadIdx.x, lane = tid & 63, wave = tid >> 6;
    int g = lane >> 4, qi = lane & 15;

    const unsigned short* Kbase = Kb + (size_t)bh * Sv * Dv;
    const unsigned short* Vtbase = Vtb + (size_t)bh * Dv * Sv;

    // Q fragment (B-operand): col=q=qi, k=d=32c+8g+j
    int qrow = q0 + (wave << 4) + qi;
    bf16x8 qf[2];
#pragma unroll
    for (int c = 0; c < 2; ++c)
        qf[c] = *(const bf16x8*)(Qb + ((size_t)bh * Sv + qrow) * Dv + (c << 5) + (g << 3));

    // precompute per-j staging source pointers (advance per kv-tile)
    const char* src[4];
    int strd[4];
    int ldsoff[4];
#pragma unroll
    for (int j = 0; j < 4; ++j) {
        int off = ((wave << 2) + j) << 10;
        int loff = off + lane * 16;
        ldsoff[j] = off;
        if (off < 8192) {  // K region: [kv][128B], row stride per tile = 64 rows
            int r = loff >> 7, cb = loff & 127;
            src[j] = (const char*)(Kbase + (size_t)r * Dv) + (cb ^ ((r & 7) << 4));
            strd[j] = 64 * Dv * 2;  // 8192 B per kv-tile
        } else {           // Vt region: [d][2B*kv]
            int lo2 = loff - 8192;
            int r = lo2 >> 7, cb = lo2 & 127;
            src[j] = (const char*)(Vtbase + (size_t)r * Sv) + (cb ^ ((r & 7) << 4));
            strd[j] = 64 * 2;       // 128 B per kv-tile
        }
    }

    float m = -1e30f, l = 0.f;
    f32x4 o[4];
    f32x4 zero = {0.f, 0.f, 0.f, 0.f};
#pragma unroll
    for (int nf = 0; nf < 4; ++nf) o[nf] = zero;

    bool hih = lane >= 32;
    bool odd = g & 1;

    // prologue stage tile 0 into buf 0
#pragma unroll
    for (int j = 0; j < 4; ++j) gload16(src[j], smem + ldsoff[j]);
    __syncthreads();

    for (int kt = 0; kt < 64; ++kt) {
        // issue next tile's loads into the other buffer (overlap with compute)
        if (kt < 63) {
            int nb = (kt + 1) & 1;
#pragma unroll
            for (int j = 0; j < 4; ++j)
                gload16(src[j] + (size_t)(kt + 1) * strd[j], smem + nb * 16384 + ldsoff[j]);
        }
        char* Ks = smem + (kt & 1) * 16384;
        char* Vs = Ks + 8192;

        // QK^T swapped: sc[nf] = K_tile(nf) . Q^T  -> P^T[kv][q]
        f32x4 sc[4];
#pragma unroll
        for (int nf = 0; nf < 4; ++nf) {
            sc[nf] = zero;
#pragma unroll
            for (int c = 0; c < 2; ++c) {
                int kr = (nf << 4) + qi;
                int colb = (c << 6) + (g << 4);
                bf16x8 kf = *(const bf16x8*)(Ks + kr * 128 + (colb ^ ((kr & 7) << 4)));
                sc[nf] = __builtin_amdgcn_mfma_f32_16x16x32_bf16(kf, qf[c], sc[nf], 0, 0, 0);
            }
        }

        // online softmax in exp2 domain; each lane owns 16 kv values of one q-row
        float pm = sc[0][0];
#pragma unroll
        for (int nf = 0; nf < 4; ++nf)
#pragma unroll
            for (int i = 0; i < 4; ++i) pm = fmaxf(pm, sc[nf][i]);
        pm = fmaxf(pm, __shfl_xor(pm, 16, 64));
        pm = fmaxf(pm, __shfl_xor(pm, 32, 64));

        if (!__all(pm - m <= 8.0f)) {  // defer-max: skip rescale on small growth
            float nm = fmaxf(m, pm);
            float corr = exp2f(m - nm);
            l *= corr;
#pragma unroll
            for (int nf = 0; nf < 4; ++nf)
#pragma unroll
                for (int i = 0; i < 4; ++i) o[nf][i] *= corr;
            m = nm;
        }

        float ps = 0.f;
#pragma unroll
        for (int nf = 0; nf < 4; ++nf)
#pragma unroll
            for (int i = 0; i < 4; ++i) {
                float p = exp2f(sc[nf][i] - m);
                sc[nf][i] = p;
                ps += p;
            }
        ps += __shfl_xor(ps, 16, 64);
        ps += __shfl_xor(ps, 32, 64);
        l += ps;

        // pack P^T -> PV B-operand fragments (in-register, no LDS)
        unsigned int Wl[4], Wh[4];
#pragma unroll
        for (int nf = 0; nf < 4; ++nf) {
            Wl[nf] = cvtpk(sc[nf][0], sc[nf][1]);
            Wh[nf] = cvtpk(sc[nf][2], sc[nf][3]);
        }
        bf16x8 pfrag[2];
#pragma unroll
        for (int ch = 0; ch < 2; ++ch) {
            unsigned int w0l = Wl[2 * ch], w0h = Wh[2 * ch];
            unsigned int w1l = Wl[2 * ch + 1], w1h = Wh[2 * ch + 1];
            unsigned int s0l = __shfl_xor(w0l, 32, 64), s0h = __shfl_xor(w0h, 32, 64);
            unsigned int s1l = __shfl_xor(w1l, 32, 64), s1h = __shfl_xor(w1h, 32, 64);
            unsigned int A0 = hih ? s1l : w0l, A1 = hih ? s1h : w0h;
            unsigned int B0 = hih ? w1l : s0l, B1 = hih ? w1h : s0h;
            unsigned int A0x = __shfl_xor(A0, 16, 64), A1x = __shfl_xor(A1, 16, 64);
            unsigned int B0x = __shfl_xor(B0, 16, 64), B1x = __shfl_xor(B1, 16, 64);
            u32x4v uu;
            uu[0] = odd ? B0x : A0;
            uu[1] = odd ? B1x : A1;
            uu[2] = odd ? B0 : A0x;
            uu[3] = odd ? B1 : A1x;
            pfrag[ch] = __builtin_bit_cast(bf16x8, uu);
        }

        // PV: o^T[d][q] += Vt_tile(nf) . P^T
#pragma unroll
        for (int c = 0; c < 2; ++c)
#pragma unroll
            for (int nf = 0; nf < 4; ++nf) {
                int dr = (nf << 4) + qi;
                int colb = (c << 6) + (g << 4);
                bf16x8 vf = *(const bf16x8*)(Vs + dr * 128 + (colb ^ ((dr & 7) << 4)));
                o[nf] = __builtin_amdgcn_mfma_f32_16x16x32_bf16(vf, pfrag[c], o[nf], 0, 0, 0);
            }

        __syncthreads();  // implicit vmcnt(0): next tile's loads landed; cur reads done
    }

    float inv = 1.f / l;
    int s = q0 + (wave << 4) + qi;
#pragma unroll
    for (int nf = 0; nf < 4; ++nf)
#pragma unroll
        for (int i = 0; i < 4; ++i) {
            int d = (nf << 4) + (g << 2) + i;
            ctx[((size_t)b * Sv + s) * Ev + (h << 6) + d] = f2bf(o[nf][i] * inv);
        }
}

// ---------------- LayerNorm (1 wave / row of 512) ----------------
__global__ __launch_bounds__(256) void k_ln(const float* __restrict__ in,
                                            const float* __restrict__ g,
                                            const float* __restrict__ bta,
                                            float* __restrict__ out) {
    int wave = threadIdx.x >> 6, lane = threadIdx.x & 63;
    size_t row = (size_t)blockIdx.x * 4 + wave;
    const float* p = in + row * 512 + lane * 8;
    float4v v0 = *(const float4v*)p;
    float4v v1 = *(const float4v*)(p + 4);
    float s = 0.f, q = 0.f;
#pragma unroll
    for (int j = 0; j < 4; ++j) {
        s += v0[j] + v1[j];
        q += v0[j] * v0[j] + v1[j] * v1[j];
    }
#pragma unroll
    for (int off = 1; off < 64; off <<= 1) {
        s += __shfl_xor(s, off, 64);
        q += __shfl_xor(q, off, 64);
    }
    float mu = s * (1.f / 512.f);
    float var = q * (1.f / 512.f) - mu * mu;
    float rs = rsqrtf(var + 1e-5f);
    int c = lane * 8;
    float4v o0, o1;
#pragma unroll
    for (int j = 0; j < 4; ++j) {
        o0[j] = (v0[j] - mu) * rs * g[c + j] + bta[c + j];
        o1[j] = (v1[j] - mu) * rs * g[c + 4 + j] + bta[c + 4 + j];
    }
    *(float4v*)(out + row * 512 + c) = o0;
    *(float4v*)(out + row * 512 + c + 4) = o1;
}

extern "C" void kernel_launch(void* const* d_in, const int* in_sizes, int n_in,
                              void* d_out, int out_size, void* d_ws, size_t ws_size,
                              hipStream_t stream) {
    const float* x     = (const float*)d_in[0];
    const float* qkv_w = (const float*)d_in[1];
    const float* qkv_b = (const float*)d_in[2];
    const float* out_w = (const float*)d_in[3];
    const float* out_b = (const float*)d_in[4];
    const float* ln_g  = (const float*)d_in[5];
    const float* ln_b  = (const float*)d_in[6];
    float* out = (float*)d_out;
    char* ws = (char*)d_ws;

    unsigned short* xb    = (unsigned short*)(ws);              // 8 MB
    unsigned short* wqkvT = (unsigned short*)(ws + 8388608);    // 1.5 MB
    unsigned short* owT   = (unsigned short*)(ws + 9961472);    // 0.5 MB
    unsigned short* Qb    = (unsigned short*)(ws + 10485760);   // 8 MB
    unsigned short* Kb    = (unsigned short*)(ws + 18874368);   // 8 MB
    unsigned short* Vb    = (unsigned short*)(ws + 27262976);   // 8 MB
    unsigned short* Vtb   = (unsigned short*)(ws + 35651584);   // 8 MB
    unsigned short* ctxb  = (unsigned short*)(ws + 44040192);   // 8 MB
    float* tmp            = (float*)(ws + 52428800);            // 16 MB

    k_convert<<<2048, 256, 0, stream>>>(x, xb, Mv * Ev / 4);
    k_tconv<<<(512 / 32) * (1536 / 32), 256, 0, stream>>>(qkv_w, wqkvT, 512, 1536);
    k_tconv<<<(512 / 32) * (512 / 32), 256, 0, stream>>>(out_w, owT, 512, 512);
    k_gemm<0><<<(Mv / 128) * (N3v / 128), 256, 0, stream>>>(
        xb, wqkvT, Mv, N3v, Ev, qkv_b, Qb, Kb, Vb, nullptr, nullptr);
    k_transpose_v<<<16 * 64, 256, 0, stream>>>(Vb, Vtb);
    k_attn<<<16 * 64, 256, 0, stream>>>(Qb, Kb, Vtb, ctxb);
    k_gemm<1><<<(Mv / 128) * (Ev / 128), 256, 0, stream>>>(
        ctxb, owT, Mv, Ev, Ev, out_b, nullptr, nullptr, nullptr, x, tmp);
    k_ln<<<Mv / 4, 256, 0, stream>>>(tmp, ln_g, ln_b, out);
}

// Round 3
// 164.809 us; speedup vs baseline: 1.8335x; 1.5025x over previous
//
#include <hip/hip_runtime.h>
#include <stdint.h>

typedef __bf16 bf16x8 __attribute__((ext_vector_type(8)));
typedef float f32x4 __attribute__((ext_vector_type(4)));
typedef float f32x16 __attribute__((ext_vector_type(16)));
typedef float float4v __attribute__((ext_vector_type(4)));
typedef unsigned short u16x4 __attribute__((ext_vector_type(4)));
typedef unsigned short u16x8 __attribute__((ext_vector_type(8)));
typedef unsigned int u32x4v __attribute__((ext_vector_type(4)));

#define DEVI __device__ __forceinline__

static constexpr int Bv = 2, Sv = 4096, Ev = 512, Hv = 8, Dv = 64;
static constexpr int Mv = Bv * Sv;   // 8192
static constexpr int N3v = 3 * Ev;   // 1536
// Q pre-scale: D^-0.5 * log2(e) so softmax runs in exp2 domain
static constexpr float QSCALE = 0.125f * 1.4426950408889634f;
static constexpr float C0 = -8.0f;   // uniform exp2 offset (cancels in o/l)

#if __has_builtin(__builtin_amdgcn_exp2f)
#define EXP2F(x) __builtin_amdgcn_exp2f(x)
#else
#define EXP2F(x) exp2f(x)
#endif

DEVI unsigned short f2bf(float f) {
    unsigned int u = __builtin_bit_cast(unsigned int, f);
    u += 0x7fffu + ((u >> 16) & 1u);
    return (unsigned short)(u >> 16);
}

DEVI unsigned int cvtpk(float lo, float hi) {
    unsigned int r;
    asm("v_cvt_pk_bf16_f32 %0, %1, %2" : "=v"(r) : "v"(lo), "v"(hi));
    return r;
}

DEVI void gload16(const void* src, void* lds) {
    __builtin_amdgcn_global_load_lds(
        (const __attribute__((address_space(1))) unsigned int*)src,
        (__attribute__((address_space(3))) unsigned int*)lds,
        16, 0, 0);
}

// ---------------- convert fp32 -> bf16 (flat) ----------------
__global__ __launch_bounds__(256) void k_convert(const float* __restrict__ in,
                                                 unsigned short* __restrict__ out, int n4) {
    int i = blockIdx.x * 256 + threadIdx.x;
    int stride = gridDim.x * 256;
    for (; i < n4; i += stride) {
        float4v v = ((const float4v*)in)[i];
        u16x4 o;
        o[0] = f2bf(v[0]); o[1] = f2bf(v[1]); o[2] = f2bf(v[2]); o[3] = f2bf(v[3]);
        ((u16x4*)out)[i] = o;
    }
}

// ---------------- transpose+convert: in fp32 [K][N] -> out bf16 [N][K] ----------------
__global__ __launch_bounds__(256) void k_tconv(const float* __restrict__ in,
                                               unsigned short* __restrict__ out, int K, int N) {
    __shared__ float lds[32][36];
    int tilesN = N >> 5;
    int tn = blockIdx.x % tilesN, tk = blockIdx.x / tilesN;
    int k0 = tk << 5, n0 = tn << 5;
    int t = threadIdx.x;
    int r = t >> 3, c4 = (t & 7) << 2;
    float4v v = *(const float4v*)(in + (size_t)(k0 + r) * N + n0 + c4);
    *(float4v*)&lds[r][c4] = v;
    __syncthreads();
    int nn = t >> 3, kc = (t & 7) << 2;
    u16x4 o;
#pragma unroll
    for (int j = 0; j < 4; ++j) o[j] = f2bf(lds[kc + j][nn]);
    *(u16x4*)(out + (size_t)(n0 + nn) * K + k0 + kc) = o;
}

// ---------------- GEMM 128x128 tile, BK=64, bf16 MFMA ----------------
template <int EPI>
__global__ __launch_bounds__(256) void k_gemm(
    const unsigned short* __restrict__ A, const unsigned short* __restrict__ Bt,
    int M, int N, int K, const float* __restrict__ bias,
    unsigned short* __restrict__ Qb, unsigned short* __restrict__ Kb,
    unsigned short* __restrict__ Vb,
    const float* __restrict__ xres, float* __restrict__ outf) {
    __shared__ char smem[32768];
    char* As = smem;
    char* Bs = smem + 16384;
    int nbt = N >> 7;
    int mb = blockIdx.x / nbt, nbi = blockIdx.x % nbt;
    int m0 = mb << 7, n0 = nbi << 7;
    int tid = threadIdx.x, lane = tid & 63, wave = tid >> 6;
    int wr = wave >> 1, wc = wave & 1;

    f32x4 acc[4][4];
    f32x4 zero = {0.f, 0.f, 0.f, 0.f};
#pragma unroll
    for (int a = 0; a < 4; ++a)
#pragma unroll
        for (int b = 0; b < 4; ++b) acc[a][b] = zero;

    for (int kt = 0; kt < K; kt += 64) {
        __syncthreads();
#pragma unroll
        for (int j = 0; j < 4; ++j) {
            int la = (((wave << 2) + j) << 10) + lane * 16;
            int r = la >> 7, cb = la & 127;
            int cbs = cb ^ ((r & 7) << 4);
            gload16((const char*)(A + (size_t)(m0 + r) * K + kt) + cbs,
                    As + (((wave << 2) + j) << 10));
            gload16((const char*)(Bt + (size_t)(n0 + r) * K + kt) + cbs,
                    Bs + (((wave << 2) + j) << 10));
        }
        asm volatile("s_waitcnt vmcnt(0)" ::: "memory");
        __syncthreads();

        bf16x8 af[4][2], bfr[4][2];
#pragma unroll
        for (int rf = 0; rf < 4; ++rf)
#pragma unroll
            for (int c = 0; c < 2; ++c) {
                int row = (wr << 6) + (rf << 4) + (lane & 15);
                int col = (c << 6) + ((lane >> 4) << 4);
                af[rf][c] = *(const bf16x8*)(As + row * 128 + (col ^ ((row & 7) << 4)));
                int rowb = (wc << 6) + (rf << 4) + (lane & 15);
                bfr[rf][c] = *(const bf16x8*)(Bs + rowb * 128 + (col ^ ((rowb & 7) << 4)));
            }
#pragma unroll
        for (int rf = 0; rf < 4; ++rf)
#pragma unroll
            for (int nf = 0; nf < 4; ++nf)
#pragma unroll
                for (int c = 0; c < 2; ++c)
                    acc[rf][nf] = __builtin_amdgcn_mfma_f32_16x16x32_bf16(
                        af[rf][c], bfr[nf][c], acc[rf][nf], 0, 0, 0);
    }

#pragma unroll
    for (int rf = 0; rf < 4; ++rf)
#pragma unroll
        for (int nf = 0; nf < 4; ++nf)
#pragma unroll
            for (int i = 0; i < 4; ++i) {
                int row = m0 + (wr << 6) + (rf << 4) + ((lane >> 4) << 2) + i;
                int col = n0 + (wc << 6) + (nf << 4) + (lane & 15);
                float v = acc[rf][nf][i] + bias[col];
                if (EPI == 0) {
                    int reg = col >> 9, hd = col & 511;
                    int h = hd >> 6, d = hd & 63;
                    int b = row >> 12, s = row & 4095;
                    size_t idx = ((size_t)((b << 3) + h) * Sv + s) * Dv + d;
                    if (reg == 0)      Qb[idx] = f2bf(v * QSCALE);
                    else if (reg == 1) Kb[idx] = f2bf(v);
                    else               Vb[idx] = f2bf(v);
                } else {
                    v += xres[(size_t)row * N + col];
                    outf[(size_t)row * N + col] = v;
                }
            }
}

// ---------------- V [bh][s][d] -> Vt [bh][d][s] ----------------
__global__ __launch_bounds__(256) void k_transpose_v(const unsigned short* __restrict__ V,
                                                     unsigned short* __restrict__ Vt) {
    __shared__ char lds[8192];
    int bh = blockIdx.x >> 6, st = blockIdx.x & 63;
    int s0 = st << 6;
    int t = threadIdx.x;
#pragma unroll
    for (int j = 0; j < 2; ++j) {
        int r = (t >> 3) + (j << 5);
        int cb = (t & 7) << 4;
        u16x8 v = *(const u16x8*)(V + ((size_t)bh * Sv + s0 + r) * Dv + (cb >> 1));
        *(u16x8*)(lds + r * 128 + (cb ^ ((r & 7) << 4))) = v;
    }
    __syncthreads();
#pragma unroll
    for (int j = 0; j < 2; ++j) {
        int d = (t >> 3) + (j << 5);
        int ss = (t & 7) << 3;
        u16x8 o;
#pragma unroll
        for (int k = 0; k < 8; ++k) {
            int s = ss + k;
            o[k] = *(const unsigned short*)(lds + s * 128 + ((d * 2) ^ ((s & 7) << 4)));
        }
        *(u16x8*)(Vt + ((size_t)bh * Dv + d) * Sv + s0 + ss) = o;
    }
}

// ---------------- flash attention: 32x32 MFMA, 32 q/wave, no-max exp2 softmax ----------
// QK^T swapped -> P^T: q = lane&31, kv(reg r, half h) = (r&3)+8*(r>>2)+4h per 32-chunk
__global__ __launch_bounds__(256) void k_attn(const unsigned short* __restrict__ Qb,
                                              const unsigned short* __restrict__ Kb,
                                              const unsigned short* __restrict__ Vtb,
                                              unsigned short* __restrict__ ctx) {
    __shared__ char smem[32768];  // 2 bufs x (K 8KB [64kv][128B] + Vt 8KB [64d][128B])
    int bid = blockIdx.x;
    int wg = ((bid & 7) << 6) + (bid >> 3);  // bijective XCD swizzle (nwg=512)
    int bh = wg >> 5, qblk = wg & 31;
    int b = bh >> 3, h = bh & 7;
    int tid = threadIdx.x, lane = tid & 63, wave = tid >> 6;
    int l31 = lane & 31, hh = lane >> 5;
    int qrow = (qblk << 7) + (wave << 5) + l31;

    const unsigned short* Kbase = Kb + (size_t)bh * Sv * Dv;
    const unsigned short* Vtbase = Vtb + (size_t)bh * Dv * Sv;

    // Q fragments (B-operand): col=q=l31, k=d=16*tp+8*hh+j
    bf16x8 qf[4];
#pragma unroll
    for (int tp = 0; tp < 4; ++tp)
        qf[tp] = *(const bf16x8*)(Qb + ((size_t)bh * Sv + qrow) * Dv + (tp << 4) + (hh << 3));

    // staging source pointers (per lane, advance per kv-tile)
    const char* src[4];
    int strd[4];
    int ldsoff[4];
#pragma unroll
    for (int j = 0; j < 4; ++j) {
        int off = ((wave << 2) + j) << 10;
        int loff = off + lane * 16;
        ldsoff[j] = off;
        if (off < 8192) {  // K region
            int r = loff >> 7, cb = loff & 127;
            src[j] = (const char*)(Kbase + (size_t)r * Dv) + (cb ^ ((r & 7) << 4));
            strd[j] = 64 * Dv * 2;
        } else {           // Vt region
            int lo2 = loff - 8192;
            int r = lo2 >> 7, cb = lo2 & 127;
            src[j] = (const char*)(Vtbase + (size_t)r * Sv) + (cb ^ ((r & 7) << 4));
            strd[j] = 64 * 2;
        }
    }

    // precomputed swizzled LDS read offsets (loop-invariant)
    int koff[2][4], voff[2][2][2];
#pragma unroll
    for (int c = 0; c < 2; ++c) {
        int krow = (c << 5) + l31;
        int ksw = (krow & 7) << 4;
#pragma unroll
        for (int tp = 0; tp < 4; ++tp)
            koff[c][tp] = krow * 128 + (((tp << 5) + (hh << 4)) ^ ksw);
#pragma unroll
        for (int tl = 0; tl < 2; ++tl) {
            int vcb = (c << 6) + (tl << 5) + (hh << 4);
#pragma unroll
            for (int dt = 0; dt < 2; ++dt) {
                int vrow = (dt << 5) + l31;
                voff[c][tl][dt] = vrow * 128 + (vcb ^ ((vrow & 7) << 4));
            }
        }
    }

    f32x16 o[2];
#pragma unroll
    for (int dt = 0; dt < 2; ++dt)
#pragma unroll
        for (int r = 0; r < 16; ++r) o[dt][r] = 0.f;
    float lsum = 0.f;

    // prologue: stage tile 0 into buf 0
#pragma unroll
    for (int j = 0; j < 4; ++j) gload16(src[j], smem + ldsoff[j]);
    __syncthreads();

    for (int kt = 0; kt < 64; ++kt) {
        if (kt < 63) {
            int nb = (kt + 1) & 1;
#pragma unroll
            for (int j = 0; j < 4; ++j)
                gload16(src[j] + (size_t)(kt + 1) * strd[j], smem + nb * 16384 + ldsoff[j]);
        }
        char* Ks = smem + (kt & 1) * 16384;
        char* Vs = Ks + 8192;

#pragma unroll
        for (int c = 0; c < 2; ++c) {
            // QK^T for this 32-kv chunk
            bf16x8 kf[4];
#pragma unroll
            for (int tp = 0; tp < 4; ++tp)
                kf[tp] = *(const bf16x8*)(Ks + koff[c][tp]);
            f32x16 sc;
#pragma unroll
            for (int r = 0; r < 16; ++r) sc[r] = C0;
#pragma unroll
            for (int tp = 0; tp < 4; ++tp)
                sc = __builtin_amdgcn_mfma_f32_32x32x16_bf16(kf[tp], qf[tp], sc, 0, 0, 0);

            // exp2 (no max tracking; C0 offset cancels in o/l)
            float p[16];
#pragma unroll
            for (int r = 0; r < 16; ++r) p[r] = EXP2F(sc[r]);
            // pairwise-tree sum
            float s0 = (p[0] + p[1]) + (p[2] + p[3]);
            float s1 = (p[4] + p[5]) + (p[6] + p[7]);
            float s2 = (p[8] + p[9]) + (p[10] + p[11]);
            float s3 = (p[12] + p[13]) + (p[14] + p[15]);
            lsum += (s0 + s1) + (s2 + s3);

            // pack to bf16 words
            unsigned int W[8];
#pragma unroll
            for (int i = 0; i < 8; ++i) W[i] = cvtpk(p[2 * i], p[2 * i + 1]);

            // per 16-kv k-step: 2 permlane32_swap build the B-operand fragment
#pragma unroll
            for (int tl = 0; tl < 2; ++tl) {
                unsigned int a1 = W[4 * tl], b1 = W[4 * tl + 2];
                unsigned int a2 = W[4 * tl + 1], b2 = W[4 * tl + 3];
                asm volatile("v_permlane32_swap_b32 %0, %1" : "+v"(a1), "+v"(b1));
                asm volatile("v_permlane32_swap_b32 %0, %1" : "+v"(a2), "+v"(b2));
                u32x4v uu;
                uu[0] = a1; uu[1] = a2; uu[2] = b1; uu[3] = b2;
                bf16x8 pf = __builtin_bit_cast(bf16x8, uu);
#pragma unroll
                for (int dt = 0; dt < 2; ++dt) {
                    bf16x8 vf = *(const bf16x8*)(Vs + voff[c][tl][dt]);
                    o[dt] = __builtin_amdgcn_mfma_f32_32x32x16_bf16(vf, pf, o[dt], 0, 0, 0);
                }
            }
        }
        __syncthreads();  // drains staging vmcnt; next tile ready
    }

    lsum += __shfl_xor(lsum, 32, 64);
    float inv = 1.f / lsum;
    size_t obase = ((size_t)b * Sv + qrow) * Ev + (h << 6);
#pragma unroll
    for (int dt = 0; dt < 2; ++dt)
#pragma unroll
        for (int rp = 0; rp < 8; ++rp) {
            int r = rp << 1;
            int d = (dt << 5) + (r & 3) + ((r >> 2) << 3) + (hh << 2);
            unsigned int w = cvtpk(o[dt][r] * inv, o[dt][r + 1] * inv);
            *(unsigned int*)(ctx + obase + d) = w;
        }
}

// ---------------- LayerNorm (1 wave / row of 512) ----------------
__global__ __launch_bounds__(256) void k_ln(const float* __restrict__ in,
                                            const float* __restrict__ g,
                                            const float* __restrict__ bta,
                                            float* __restrict__ out) {
    int wave = threadIdx.x >> 6, lane = threadIdx.x & 63;
    size_t row = (size_t)blockIdx.x * 4 + wave;
    const float* p = in + row * 512 + lane * 8;
    float4v v0 = *(const float4v*)p;
    float4v v1 = *(const float4v*)(p + 4);
    float s = 0.f, q = 0.f;
#pragma unroll
    for (int j = 0; j < 4; ++j) {
        s += v0[j] + v1[j];
        q += v0[j] * v0[j] + v1[j] * v1[j];
    }
#pragma unroll
    for (int off = 1; off < 64; off <<= 1) {
        s += __shfl_xor(s, off, 64);
        q += __shfl_xor(q, off, 64);
    }
    float mu = s * (1.f / 512.f);
    float var = q * (1.f / 512.f) - mu * mu;
    float rs = rsqrtf(var + 1e-5f);
    int c = lane * 8;
    float4v o0, o1;
#pragma unroll
    for (int j = 0; j < 4; ++j) {
        o0[j] = (v0[j] - mu) * rs * g[c + j] + bta[c + j];
        o1[j] = (v1[j] - mu) * rs * g[c + 4 + j] + bta[c + 4 + j];
    }
    *(float4v*)(out + row * 512 + c) = o0;
    *(float4v*)(out + row * 512 + c + 4) = o1;
}

extern "C" void kernel_launch(void* const* d_in, const int* in_sizes, int n_in,
                              void* d_out, int out_size, void* d_ws, size_t ws_size,
                              hipStream_t stream) {
    const float* x     = (const float*)d_in[0];
    const float* qkv_w = (const float*)d_in[1];
    const float* qkv_b = (const float*)d_in[2];
    const float* out_w = (const float*)d_in[3];
    const float* out_b = (const float*)d_in[4];
    const float* ln_g  = (const float*)d_in[5];
    const float* ln_b  = (const float*)d_in[6];
    float* out = (float*)d_out;
    char* ws = (char*)d_ws;

    unsigned short* xb    = (unsigned short*)(ws);              // 8 MB
    unsigned short* wqkvT = (unsigned short*)(ws + 8388608);    // 1.5 MB
    unsigned short* owT   = (unsigned short*)(ws + 9961472);    // 0.5 MB
    unsigned short* Qb    = (unsigned short*)(ws + 10485760);   // 8 MB
    unsigned short* Kb    = (unsigned short*)(ws + 18874368);   // 8 MB
    unsigned short* Vb    = (unsigned short*)(ws + 27262976);   // 8 MB
    unsigned short* Vtb   = (unsigned short*)(ws + 35651584);   // 8 MB
    unsigned short* ctxb  = (unsigned short*)(ws + 44040192);   // 8 MB
    float* tmp            = (float*)(ws + 52428800);            // 16 MB

    k_convert<<<2048, 256, 0, stream>>>(x, xb, Mv * Ev / 4);
    k_tconv<<<(512 / 32) * (1536 / 32), 256, 0, stream>>>(qkv_w, wqkvT, 512, 1536);
    k_tconv<<<(512 / 32) * (512 / 32), 256, 0, stream>>>(out_w, owT, 512, 512);
    k_gemm<0><<<(Mv / 128) * (N3v / 128), 256, 0, stream>>>(
        xb, wqkvT, Mv, N3v, Ev, qkv_b, Qb, Kb, Vb, nullptr, nullptr);
    k_transpose_v<<<16 * 64, 256, 0, stream>>>(Vb, Vtb);
    k_attn<<<512, 256, 0, stream>>>(Qb, Kb, Vtb, ctxb);
    k_gemm<1><<<(Mv / 128) * (Ev / 128), 256, 0, stream>>>(
        ctxb, owT, Mv, Ev, Ev, out_b, nullptr, nullptr, nullptr, x, tmp);
    k_ln<<<Mv / 4, 256, 0, stream>>>(tmp, ln_g, ln_b, out);
}

// Round 4
// 160.831 us; speedup vs baseline: 1.8789x; 1.0247x over previous
//
#include <hip/hip_runtime.h>
#include <stdint.h>

typedef __bf16 bf16x8 __attribute__((ext_vector_type(8)));
typedef float f32x4 __attribute__((ext_vector_type(4)));
typedef float f32x16 __attribute__((ext_vector_type(16)));
typedef float float4v __attribute__((ext_vector_type(4)));
typedef unsigned short u16x4 __attribute__((ext_vector_type(4)));
typedef unsigned short u16x8 __attribute__((ext_vector_type(8)));
typedef unsigned int u32x4v __attribute__((ext_vector_type(4)));

#define DEVI __device__ __forceinline__

static constexpr int Bv = 2, Sv = 4096, Ev = 512, Hv = 8, Dv = 64;
static constexpr int Mv = Bv * Sv;   // 8192
static constexpr int N3v = 3 * Ev;   // 1536
static constexpr float QSCALE = 0.125f * 1.4426950408889634f;  // exp2-domain
static constexpr float C0 = -8.0f;   // uniform exp2 offset (cancels in o/l)

#if __has_builtin(__builtin_amdgcn_exp2f)
#define EXP2F(x) __builtin_amdgcn_exp2f(x)
#else
#define EXP2F(x) exp2f(x)
#endif

DEVI unsigned short f2bf(float f) {
    unsigned int u = __builtin_bit_cast(unsigned int, f);
    u += 0x7fffu + ((u >> 16) & 1u);
    return (unsigned short)(u >> 16);
}

DEVI float b2f(unsigned short u) {
    return __builtin_bit_cast(float, (unsigned int)u << 16);
}

DEVI unsigned int cvtpk(float lo, float hi) {
    unsigned int r;
    asm("v_cvt_pk_bf16_f32 %0, %1, %2" : "=v"(r) : "v"(lo), "v"(hi));
    return r;
}

DEVI void gload16(const void* src, void* lds) {
    __builtin_amdgcn_global_load_lds(
        (const __attribute__((address_space(1))) unsigned int*)src,
        (__attribute__((address_space(3))) unsigned int*)lds,
        16, 0, 0);
}

// ---------------- convert fp32 -> bf16 (flat) ----------------
__global__ __launch_bounds__(256) void k_convert(const float* __restrict__ in,
                                                 unsigned short* __restrict__ out, int n4) {
    int i = blockIdx.x * 256 + threadIdx.x;
    int stride = gridDim.x * 256;
    for (; i < n4; i += stride) {
        float4v v = ((const float4v*)in)[i];
        u16x4 o;
        o[0] = f2bf(v[0]); o[1] = f2bf(v[1]); o[2] = f2bf(v[2]); o[3] = f2bf(v[3]);
        ((u16x4*)out)[i] = o;
    }
}

// ---------------- transpose+convert: in fp32 [K][N] -> out bf16 [N][K] ----------------
__global__ __launch_bounds__(256) void k_tconv(const float* __restrict__ in,
                                               unsigned short* __restrict__ out, int K, int N) {
    __shared__ float lds[32][36];
    int tilesN = N >> 5;
    int tn = blockIdx.x % tilesN, tk = blockIdx.x / tilesN;
    int k0 = tk << 5, n0 = tn << 5;
    int t = threadIdx.x;
    int r = t >> 3, c4 = (t & 7) << 2;
    float4v v = *(const float4v*)(in + (size_t)(k0 + r) * N + n0 + c4);
    *(float4v*)&lds[r][c4] = v;
    __syncthreads();
    int nn = t >> 3, kc = (t & 7) << 2;
    u16x4 o;
#pragma unroll
    for (int j = 0; j < 4; ++j) o[j] = f2bf(lds[kc + j][nn]);
    *(u16x4*)(out + (size_t)(n0 + nn) * K + k0 + kc) = o;
}

// ---------------- GEMM 128x128 tile, BK=64, bf16 MFMA ----------------
// EPI 0: QKV scatter (V written TRANSPOSED [bh][d][s]). EPI 1: proj+residual.
template <int EPI>
__global__ __launch_bounds__(256) void k_gemm(
    const unsigned short* __restrict__ A, const unsigned short* __restrict__ Bt,
    int M, int N, int K, const float* __restrict__ bias,
    unsigned short* __restrict__ Qb, unsigned short* __restrict__ Kb,
    unsigned short* __restrict__ Vtb,
    const float* __restrict__ xres, float* __restrict__ outf) {
    __shared__ char smem[32768];
    char* As = smem;
    char* Bs = smem + 16384;
    int nbt = N >> 7;
    int mb = blockIdx.x / nbt, nbi = blockIdx.x % nbt;
    int m0 = mb << 7, n0 = nbi << 7;
    int tid = threadIdx.x, lane = tid & 63, wave = tid >> 6;
    int wr = wave >> 1, wc = wave & 1;

    f32x4 acc[4][4];
    f32x4 zero = {0.f, 0.f, 0.f, 0.f};
#pragma unroll
    for (int a = 0; a < 4; ++a)
#pragma unroll
        for (int b = 0; b < 4; ++b) acc[a][b] = zero;

    for (int kt = 0; kt < K; kt += 64) {
        __syncthreads();
#pragma unroll
        for (int j = 0; j < 4; ++j) {
            int la = (((wave << 2) + j) << 10) + lane * 16;
            int r = la >> 7, cb = la & 127;
            int cbs = cb ^ ((r & 7) << 4);
            gload16((const char*)(A + (size_t)(m0 + r) * K + kt) + cbs,
                    As + (((wave << 2) + j) << 10));
            gload16((const char*)(Bt + (size_t)(n0 + r) * K + kt) + cbs,
                    Bs + (((wave << 2) + j) << 10));
        }
        asm volatile("s_waitcnt vmcnt(0)" ::: "memory");
        __syncthreads();

        bf16x8 af[4][2], bfr[4][2];
#pragma unroll
        for (int rf = 0; rf < 4; ++rf)
#pragma unroll
            for (int c = 0; c < 2; ++c) {
                int row = (wr << 6) + (rf << 4) + (lane & 15);
                int col = (c << 6) + ((lane >> 4) << 4);
                af[rf][c] = *(const bf16x8*)(As + row * 128 + (col ^ ((row & 7) << 4)));
                int rowb = (wc << 6) + (rf << 4) + (lane & 15);
                bfr[rf][c] = *(const bf16x8*)(Bs + rowb * 128 + (col ^ ((rowb & 7) << 4)));
            }
#pragma unroll
        for (int rf = 0; rf < 4; ++rf)
#pragma unroll
            for (int nf = 0; nf < 4; ++nf)
#pragma unroll
                for (int c = 0; c < 2; ++c)
                    acc[rf][nf] = __builtin_amdgcn_mfma_f32_16x16x32_bf16(
                        af[rf][c], bfr[nf][c], acc[rf][nf], 0, 0, 0);
    }

#pragma unroll
    for (int rf = 0; rf < 4; ++rf)
#pragma unroll
        for (int nf = 0; nf < 4; ++nf) {
            int row0 = m0 + (wr << 6) + (rf << 4) + ((lane >> 4) << 2);
            int col = n0 + (wc << 6) + (nf << 4) + (lane & 15);
            float bv = bias[col];
            if (EPI == 0) {
                int reg = col >> 9, hd = col & 511;
                int h = hd >> 6, d = hd & 63;
                int b = row0 >> 12, s0 = row0 & 4095;
                if (reg == 2) {
                    u16x4 o4;
#pragma unroll
                    for (int i = 0; i < 4; ++i) o4[i] = f2bf(acc[rf][nf][i] + bv);
                    *(u16x4*)(Vtb + ((size_t)((b << 3) + h) * 64 + d) * 4096 + s0) = o4;
                } else {
#pragma unroll
                    for (int i = 0; i < 4; ++i) {
                        float v = acc[rf][nf][i] + bv;
                        size_t idx = ((size_t)((b << 3) + h) * Sv + s0 + i) * Dv + d;
                        if (reg == 0) Qb[idx] = f2bf(v * QSCALE);
                        else          Kb[idx] = f2bf(v);
                    }
                }
            } else {
#pragma unroll
                for (int i = 0; i < 4; ++i) {
                    int row = row0 + i;
                    float v = acc[rf][nf][i] + bv + xres[(size_t)row * N + col];
                    outf[(size_t)row * N + col] = v;
                }
            }
        }
}

// ---------------- flash attention: 32x32 MFMA, KV-split x2, no-max exp2 ----------
// partials: po[half][bh][s][64] bf16 (unscaled o), pl[half][bh][s] f32 (l sums)
__global__ __launch_bounds__(256) void k_attn(const unsigned short* __restrict__ Qb,
                                              const unsigned short* __restrict__ Kb,
                                              const unsigned short* __restrict__ Vtb,
                                              unsigned short* __restrict__ po,
                                              float* __restrict__ pl) {
    __shared__ char smem[32768];  // 2 bufs x (K 8KB [64kv][128B] + Vt 8KB [64d][128B])
    int bid = blockIdx.x;
    int wg = ((bid & 7) << 7) + (bid >> 3);  // bijective XCD swizzle (nwg=1024)
    int half = wg & 1, qblk = (wg >> 1) & 31, bh = wg >> 6;
    int tid = threadIdx.x, lane = tid & 63, wave = tid >> 6;
    int l31 = lane & 31, hh = lane >> 5;
    int qrow = (qblk << 7) + (wave << 5) + l31;
    int kvbase = half << 11;  // 0 or 2048

    const unsigned short* Kbase = Kb + (size_t)bh * Sv * Dv + (size_t)kvbase * Dv;
    const unsigned short* Vtbase = Vtb + (size_t)bh * Dv * Sv + kvbase;

    bf16x8 qf[4];
#pragma unroll
    for (int tp = 0; tp < 4; ++tp)
        qf[tp] = *(const bf16x8*)(Qb + ((size_t)bh * Sv + qrow) * Dv + (tp << 4) + (hh << 3));

    const char* src[4];
    int strd[4];
    int ldsoff[4];
#pragma unroll
    for (int j = 0; j < 4; ++j) {
        int off = ((wave << 2) + j) << 10;
        int loff = off + lane * 16;
        ldsoff[j] = off;
        if (off < 8192) {  // K region
            int r = loff >> 7, cb = loff & 127;
            src[j] = (const char*)(Kbase + (size_t)r * Dv) + (cb ^ ((r & 7) << 4));
            strd[j] = 64 * Dv * 2;
        } else {           // Vt region
            int lo2 = loff - 8192;
            int r = lo2 >> 7, cb = lo2 & 127;
            src[j] = (const char*)(Vtbase + (size_t)r * Sv) + (cb ^ ((r & 7) << 4));
            strd[j] = 64 * 2;
        }
    }

    int koff[2][4], voff[2][2][2];
#pragma unroll
    for (int c = 0; c < 2; ++c) {
        int krow = (c << 5) + l31;
        int ksw = (krow & 7) << 4;
#pragma unroll
        for (int tp = 0; tp < 4; ++tp)
            koff[c][tp] = krow * 128 + (((tp << 5) + (hh << 4)) ^ ksw);
#pragma unroll
        for (int tl = 0; tl < 2; ++tl) {
            int vcb = (c << 6) + (tl << 5) + (hh << 4);
#pragma unroll
            for (int dt = 0; dt < 2; ++dt) {
                int vrow = (dt << 5) + l31;
                voff[c][tl][dt] = vrow * 128 + (vcb ^ ((vrow & 7) << 4));
            }
        }
    }

    f32x16 o[2];
#pragma unroll
    for (int dt = 0; dt < 2; ++dt)
#pragma unroll
        for (int r = 0; r < 16; ++r) o[dt][r] = 0.f;
    float lsum = 0.f;

#pragma unroll
    for (int j = 0; j < 4; ++j) gload16(src[j], smem + ldsoff[j]);
    __syncthreads();

    for (int kt = 0; kt < 32; ++kt) {
        if (kt < 31) {
            int nb = (kt + 1) & 1;
#pragma unroll
            for (int j = 0; j < 4; ++j)
                gload16(src[j] + (size_t)(kt + 1) * strd[j], smem + nb * 16384 + ldsoff[j]);
        }
        char* Ks = smem + (kt & 1) * 16384;
        char* Vs = Ks + 8192;

#pragma unroll
        for (int c = 0; c < 2; ++c) {
            bf16x8 kf[4];
#pragma unroll
            for (int tp = 0; tp < 4; ++tp)
                kf[tp] = *(const bf16x8*)(Ks + koff[c][tp]);
            f32x16 sc;
#pragma unroll
            for (int r = 0; r < 16; ++r) sc[r] = C0;
            __builtin_amdgcn_s_setprio(1);
#pragma unroll
            for (int tp = 0; tp < 4; ++tp)
                sc = __builtin_amdgcn_mfma_f32_32x32x16_bf16(kf[tp], qf[tp], sc, 0, 0, 0);
            __builtin_amdgcn_s_setprio(0);

            float p[16];
#pragma unroll
            for (int r = 0; r < 16; ++r) p[r] = EXP2F(sc[r]);
            float s0 = (p[0] + p[1]) + (p[2] + p[3]);
            float s1 = (p[4] + p[5]) + (p[6] + p[7]);
            float s2 = (p[8] + p[9]) + (p[10] + p[11]);
            float s3 = (p[12] + p[13]) + (p[14] + p[15]);
            lsum += (s0 + s1) + (s2 + s3);

            unsigned int W[8];
#pragma unroll
            for (int i = 0; i < 8; ++i) W[i] = cvtpk(p[2 * i], p[2 * i + 1]);

#pragma unroll
            for (int tl = 0; tl < 2; ++tl) {
                unsigned int a1 = W[4 * tl], b1 = W[4 * tl + 2];
                unsigned int a2 = W[4 * tl + 1], b2 = W[4 * tl + 3];
                asm volatile("v_permlane32_swap_b32 %0, %1" : "+v"(a1), "+v"(b1));
                asm volatile("v_permlane32_swap_b32 %0, %1" : "+v"(a2), "+v"(b2));
                u32x4v uu;
                uu[0] = a1; uu[1] = a2; uu[2] = b1; uu[3] = b2;
                bf16x8 pf = __builtin_bit_cast(bf16x8, uu);
                __builtin_amdgcn_s_setprio(1);
#pragma unroll
                for (int dt = 0; dt < 2; ++dt) {
                    bf16x8 vf = *(const bf16x8*)(Vs + voff[c][tl][dt]);
                    o[dt] = __builtin_amdgcn_mfma_f32_32x32x16_bf16(vf, pf, o[dt], 0, 0, 0);
                }
                __builtin_amdgcn_s_setprio(0);
            }
        }
        __syncthreads();
    }

    lsum += __shfl_xor(lsum, 32, 64);
    if (!hh) pl[((size_t)half * 16 + bh) * Sv + qrow] = lsum;
    size_t obase = (((size_t)half * 16 + bh) * Sv + qrow) * 64;
#pragma unroll
    for (int dt = 0; dt < 2; ++dt)
#pragma unroll
        for (int rp = 0; rp < 8; ++rp) {
            int r = rp << 1;
            int d = (dt << 5) + (r & 3) + ((r >> 2) << 3) + (hh << 2);
            unsigned int w = cvtpk(o[dt][r], o[dt][r + 1]);
            *(unsigned int*)(po + obase + d) = w;
        }
}

// ---------------- merge: ctx = (o0+o1)/(l0+l1), bf16 out ----------------
__global__ __launch_bounds__(256) void k_merge(const unsigned short* __restrict__ po,
                                               const float* __restrict__ pl,
                                               unsigned short* __restrict__ ctx) {
    int t = blockIdx.x * 256 + threadIdx.x;  // 16*4096*8 threads
    int d8 = t & 7, s = (t >> 3) & 4095, bh = t >> 15;
    int b = bh >> 3, h = bh & 7;
    size_t r0 = ((size_t)bh * 4096 + s) * 64 + (d8 << 3);
    size_t r1 = r0 + (size_t)16 * 4096 * 64;
    u16x8 pa = *(const u16x8*)(po + r0);
    u16x8 pb = *(const u16x8*)(po + r1);
    float inv = 1.f / (pl[(size_t)bh * 4096 + s] + pl[(size_t)16 * 4096 + bh * 4096 + s]);
    u32x4v w;
#pragma unroll
    for (int j = 0; j < 4; ++j) {
        float lo = (b2f(pa[2 * j]) + b2f(pb[2 * j])) * inv;
        float hi = (b2f(pa[2 * j + 1]) + b2f(pb[2 * j + 1])) * inv;
        w[j] = cvtpk(lo, hi);
    }
    *(u32x4v*)(ctx + ((size_t)b * 4096 + s) * 512 + (h << 6) + (d8 << 3)) = w;
}

// ---------------- LayerNorm (1 wave / row of 512) ----------------
__global__ __launch_bounds__(256) void k_ln(const float* __restrict__ in,
                                            const float* __restrict__ g,
                                            const float* __restrict__ bta,
                                            float* __restrict__ out) {
    int wave = threadIdx.x >> 6, lane = threadIdx.x & 63;
    size_t row = (size_t)blockIdx.x * 4 + wave;
    const float* p = in + row * 512 + lane * 8;
    float4v v0 = *(const float4v*)p;
    float4v v1 = *(const float4v*)(p + 4);
    float s = 0.f, q = 0.f;
#pragma unroll
    for (int j = 0; j < 4; ++j) {
        s += v0[j] + v1[j];
        q += v0[j] * v0[j] + v1[j] * v1[j];
    }
#pragma unroll
    for (int off = 1; off < 64; off <<= 1) {
        s += __shfl_xor(s, off, 64);
        q += __shfl_xor(q, off, 64);
    }
    float mu = s * (1.f / 512.f);
    float var = q * (1.f / 512.f) - mu * mu;
    float rs = rsqrtf(var + 1e-5f);
    int c = lane * 8;
    float4v o0, o1;
#pragma unroll
    for (int j = 0; j < 4; ++j) {
        o0[j] = (v0[j] - mu) * rs * g[c + j] + bta[c + j];
        o1[j] = (v1[j] - mu) * rs * g[c + 4 + j] + bta[c + 4 + j];
    }
    *(float4v*)(out + row * 512 + c) = o0;
    *(float4v*)(out + row * 512 + c + 4) = o1;
}

extern "C" void kernel_launch(void* const* d_in, const int* in_sizes, int n_in,
                              void* d_out, int out_size, void* d_ws, size_t ws_size,
                              hipStream_t stream) {
    const float* x     = (const float*)d_in[0];
    const float* qkv_w = (const float*)d_in[1];
    const float* qkv_b = (const float*)d_in[2];
    const float* out_w = (const float*)d_in[3];
    const float* out_b = (const float*)d_in[4];
    const float* ln_g  = (const float*)d_in[5];
    const float* ln_b  = (const float*)d_in[6];
    float* out = (float*)d_out;
    char* ws = (char*)d_ws;

    unsigned short* xb    = (unsigned short*)(ws);              // 8 MB (dead after gemm0)
    unsigned short* wqkvT = (unsigned short*)(ws + 8388608);    // 1.5 MB
    unsigned short* owT   = (unsigned short*)(ws + 9961472);    // 0.5 MB
    unsigned short* Qb    = (unsigned short*)(ws + 10485760);   // 8 MB
    unsigned short* Kb    = (unsigned short*)(ws + 18874368);   // 8 MB
    unsigned short* Vtb   = (unsigned short*)(ws + 27262976);   // 8 MB (transposed [bh][d][s])
    unsigned short* ctxb  = (unsigned short*)(ws + 35651584);   // 8 MB
    unsigned short* po    = (unsigned short*)(ws + 44040192);   // 16 MB (2 halves x 8 MB)
    float* tmp            = (float*)(ws + 44040192);            // 16 MB (overlaps po; po dead then)
    float* pl             = (float*)(ws + 60817408);            // 512 KB

    k_convert<<<2048, 256, 0, stream>>>(x, xb, Mv * Ev / 4);
    k_tconv<<<(512 / 32) * (1536 / 32), 256, 0, stream>>>(qkv_w, wqkvT, 512, 1536);
    k_tconv<<<(512 / 32) * (512 / 32), 256, 0, stream>>>(out_w, owT, 512, 512);
    k_gemm<0><<<(Mv / 128) * (N3v / 128), 256, 0, stream>>>(
        xb, wqkvT, Mv, N3v, Ev, qkv_b, Qb, Kb, Vtb, nullptr, nullptr);
    k_attn<<<1024, 256, 0, stream>>>(Qb, Kb, Vtb, po, pl);
    k_merge<<<2048, 256, 0, stream>>>(po, pl, ctxb);
    k_gemm<1><<<(Mv / 128) * (Ev / 128), 256, 0, stream>>>(
        ctxb, owT, Mv, Ev, Ev, out_b, nullptr, nullptr, nullptr, x, tmp);
    k_ln<<<Mv / 4, 256, 0, stream>>>(tmp, ln_g, ln_b, out);
}